// Round 12
// baseline (819.255 us; speedup 1.0000x reference)
//
#include <hip/hip_runtime.h>
#include <hip/hip_bf16.h>

// KNN top-16: X_test[4096,256] vs X_train[65536,256], fp32 in, int32 idx out.
// Phase 1: fp32->bf16 convert; fp32 train row sq-norms (numpy-pairwise emulation).
// Phase 2: bf16 MFMA approx score GEMM (v = ||b||^2 - 2 a.b), SWAPPED operands
//          (R10/R11: mfma(train,test,acc) -> D[train_col][test_row]; per-thread
//          register top-16 + 4-deep shift-FIFO deferred insertion; zero
//          selection syncs; FETCH 25MB). R11 = 274us champion, VALU 55%.
//          R12: TN 128->256 (sB 64KB, ITERS 16). Halves barrier events and
//          flush count per column of work -- flush chain-inserts execute at
//          wave-any~1 regardless of rates (64-lane any), so cost scales with
//          flush COUNT, not pass rate. acc[8]->acc[16] (AGPR), 2 blocks/CU
//          kept (130KB LDS), unified regs ~124 <= 128 cap @ 4 waves/SIMD.
// Phase 3: 8 rows/block: approx-top-32 prefilter of 256 candidates (width-32
//          shuffles), then 256 parallel exact fp32-reference-emulating chains,
//          lex (d32, gidx) top-16 (fp32 snap-ties resolve by index like top_k).

typedef short bf16x8 __attribute__((ext_vector_type(8)));
typedef float f32x4 __attribute__((ext_vector_type(4)));
typedef unsigned short ushort_t;
typedef unsigned long long u64;

#define K_DIM     256
#define N_TRAIN   65536
#define N_TEST    4096
#define TM        128
#define TN        256
#define NCHUNK    16
#define CHUNK_N   (N_TRAIN / NCHUNK)      // 4096
#define ITERS     (CHUNK_N / TN)          // 16
#define LISTN     16
#define RPB       8                        // refine rows per block
#define SENT      0xFFFFFFFFu

// ---------------- numpy pairwise sum emulation (fp32, contract OFF) ----------------
static __device__ __forceinline__ float np_pw_sq128(const float* __restrict__ x) {
    #pragma clang fp contract(off)
    float r0, r1, r2, r3, r4, r5, r6, r7;
    {
        const float4 a = *(const float4*)(x + 0);
        const float4 b = *(const float4*)(x + 4);
        r0 = a.x * a.x; r1 = a.y * a.y; r2 = a.z * a.z; r3 = a.w * a.w;
        r4 = b.x * b.x; r5 = b.y * b.y; r6 = b.z * b.z; r7 = b.w * b.w;
    }
    for (int i = 8; i < 128; i += 8) {
        const float4 a = *(const float4*)(x + i);
        const float4 b = *(const float4*)(x + i + 4);
        r0 = r0 + a.x * a.x; r1 = r1 + a.y * a.y;
        r2 = r2 + a.z * a.z; r3 = r3 + a.w * a.w;
        r4 = r4 + b.x * b.x; r5 = r5 + b.y * b.y;
        r6 = r6 + b.z * b.z; r7 = r7 + b.w * b.w;
    }
    return ((r0 + r1) + (r2 + r3)) + ((r4 + r5) + (r6 + r7));
}

// ---------------- async global->LDS, 16B per lane ----------------
static __device__ __forceinline__ void gld_lds16(const ushort_t* g, ushort_t* l) {
    __builtin_amdgcn_global_load_lds(
        (const __attribute__((address_space(1))) unsigned int*)g,
        (__attribute__((address_space(3))) unsigned int*)l,
        16, 0, 0);
}

// ---------------- Phase 1a: convert ----------------
static __device__ __forceinline__ ushort_t f2bf(float x) {
    unsigned u = __float_as_uint(x);
    return (ushort_t)((u + 0x7FFFu + ((u >> 16) & 1u)) >> 16);  // RNE
}

__global__ __launch_bounds__(256) void convert_bf16(
    const float* __restrict__ src, ushort_t* __restrict__ dst, int nrows)
{
    const int wid = threadIdx.x >> 6, lane = threadIdx.x & 63;
    const int row = blockIdx.x * 4 + wid;
    if (row >= nrows) return;
    const float4 f = *(const float4*)(src + (size_t)row * K_DIM + lane * 4);
    ushort4 h;
    h.x = f2bf(f.x); h.y = f2bf(f.y); h.z = f2bf(f.z); h.w = f2bf(f.w);
    *(ushort4*)(dst + (size_t)row * K_DIM + lane * 4) = h;
}

// ---------------- Phase 1b: train row norms, numpy-pairwise fp32 ----------------
__global__ __launch_bounds__(256) void train_sq_np(
    const float* __restrict__ train, float* __restrict__ bsq)
{
    const int r = blockIdx.x * 256 + threadIdx.x;
    const float* x = train + (size_t)r * K_DIM;
    bsq[r] = np_pw_sq128(x) + np_pw_sq128(x + 128);
}

// ---------------- Phase 2: swapped-operand GEMM + FIFO-deferred register top-16 ----------------
// 512 thr, 8 waves; each wave owns 16 test rows x 256 train cols. B (train) staged
// in 64 KB LDS; A (test) preloaded; D[train_col][test_row].
__global__ __launch_bounds__(512, 4) void knn_approx(
    const ushort_t* __restrict__ testBf, const ushort_t* __restrict__ trainBf,
    const float* __restrict__ bsq, unsigned* __restrict__ cand)
{
    __shared__ __align__(16) ushort_t sB[TN * 128];    // 64 KB: 256 cols x 128 k
    __shared__ __align__(16) float    sBsq[TN];        // 1 KB (bsq + 1024)

    const int tid = threadIdx.x;
    const int bx = blockIdx.x;
    const int chunk = bx & (NCHUNK - 1);               // bx%8 = chunk%8 -> chunk-per-XCD
    const int rowTile = bx >> 4;                       // 0..31
    const int rowBase = rowTile * TM;
    const int chunkBase = chunk * CHUNK_N;
    const int lane = tid & 63;
    const int wid = tid >> 6;                          // 0..7
    const int quad = lane >> 4;
    const int l15 = lane & 15;

    // my test row (one per thread; 16 rows per wave, 8 waves = 128 rows)
    const int myRow = rowBase + wid * 16 + l15;

    // register-resident top-16 (packed keys), ascending; sentinels > any real key
    // and safe for the +0x1000 pretest reconstruction (0x7F7FF000+0x1000 = +inf).
    unsigned lk[LISTN];
    #pragma unroll
    for (int j = 0; j < LISTN; ++j) lk[j] = 0x7F7FF000u | (unsigned)j;

    // guarded chain-insert (compile-time indices only; SENT always fails guard)
    auto cins = [&](unsigned k) {
        if (k < lk[LISTN - 1]) {
            lk[LISTN - 1] = k;
            #pragma unroll
            for (int j = LISTN - 1; j > 0; --j)
                if (lk[j] < lk[j - 1]) {
                    const unsigned t = lk[j]; lk[j] = lk[j - 1]; lk[j - 1] = t;
                }
        }
    };

    // 4-deep shift FIFO of pending keys + cached float pretest cut
    unsigned q0 = SENT, q1 = SENT, q2 = SENT, q3 = SENT;
    float cutFp = __uint_as_float((lk[LISTN - 1] & 0xFFFFF000u) + 0x1000u);  // +inf

    // ---- preload A-fragments (test row myRow, all K=256; 8 frags = 32 VGPR) ----
    bf16x8 af[2][4];   // [panel][s2]; frag k = quad*8 + s2*32 + p*128
    {
        const ushort_t* a0 = testBf + (size_t)myRow * K_DIM + quad * 8;
        #pragma unroll
        for (int p = 0; p < 2; ++p)
            #pragma unroll
            for (int s2 = 0; s2 < 4; ++s2)
                af[p][s2] = *(const bf16x8*)(a0 + p * 128 + s2 * 32);
    }

    // B staging: slot s = c*512+tid -> col = c*32 + (tid>>4), group u = tid&15
    const int rt = tid >> 4;                           // 0..31
    const int ub = tid & 15;
    const int kg = ((ub & 7) ^ (rt & 7)) | (ub & 8);   // c-independent (32%8==0)

    for (int it = 0; it < ITERS; ++it) {
        const int colBase = chunkBase + it * TN;
        f32x4 acc[16] = {};                            // 16 ct-tiles x 4 cols, my row

        #pragma unroll
        for (int p = 0; p < 2; ++p) {
            __syncthreads();           // protect sB against prior panel's reads
            {
                const ushort_t* gb = trainBf + (size_t)(colBase + rt) * K_DIM + p * 128 + kg * 8;
                ushort_t* lb = sB + (size_t)tid * 8;
                #pragma unroll
                for (int c = 0; c < 8; ++c)
                    gld_lds16(gb + (size_t)c * 32 * K_DIM, lb + (size_t)c * 4096);
            }
            if (p == 0 && tid < TN) sBsq[tid] = bsq[colBase + tid] + 1024.0f;
            __syncthreads();           // drains vmcnt -> LDS valid

            #pragma unroll
            for (int s2 = 0; s2 < 4; ++s2) {
                #pragma unroll
                for (int ct = 0; ct < 16; ++ct) {
                    const int col = ct * 16 + l15;     // train col (A-operand row)
                    const int g = s2 * 4 + quad;
                    const int pg = ((g & 7) ^ (col & 7)) | (g & 8);
                    const bf16x8 bfr = *(const bf16x8*)(sB + (size_t)col * 128 + pg * 8);
                    // SWAPPED: train as A, test as B -> D[train_col][test_row]
                    acc[ct] = __builtin_amdgcn_mfma_f32_16x16x32_bf16(bfr, af[p][s2], acc[ct], 0, 0, 0);
                }
            }
        }

        // epilogue: v+1024 = fmaf(-2, dot, bsq+1024); float pretest + FIFO push
        #pragma unroll
        for (int ct = 0; ct < 16; ++ct) {
            const float4 bq4 = *(const float4*)(sBsq + ct * 16 + quad * 4);
            const unsigned colb = (unsigned)(it * TN + ct * 16 + quad * 4);
            #pragma unroll
            for (int r = 0; r < 4; ++r) {
                const float bq = (r == 0) ? bq4.x : (r == 1) ? bq4.y : (r == 2) ? bq4.z : bq4.w;
                const float v = fmaf(-2.0f, acc[ct][r], bq);
                if (v < cutFp) {                       // 1-op pretest (superset of exact)
                    cins(q3);                          // overflow-preserve (rare; SENT fails)
                    q3 = q2; q2 = q1; q1 = q0;
                    q0 = (__float_as_uint(v) & 0xFFFFF000u) | (colb + (unsigned)r);
                }
            }
        }

        // flush FIFO (oldest first); once per 64 slots
        cins(q3); cins(q2); cins(q1); cins(q0);
        q0 = SENT; q1 = SENT; q2 = SENT; q3 = SENT;
        cutFp = __uint_as_float((lk[LISTN - 1] & 0xFFFFF000u) + 0x1000u);
    }

    // ---- merge the 4 quad-partitions of my row (exact): shfl_xor 16 then 32 ----
    #pragma unroll
    for (int step = 16; step <= 32; step <<= 1) {
        unsigned other[LISTN];
        #pragma unroll
        for (int j = 0; j < LISTN; ++j)
            other[j] = (unsigned)__shfl_xor((int)lk[j], step, 64);
        unsigned c[LISTN];
        // half-cleaner: smallest 16 of (lk ∪ other); result is bitonic
        #pragma unroll
        for (int j = 0; j < LISTN; ++j) {
            const unsigned a = lk[j], b = other[LISTN - 1 - j];
            c[j] = a < b ? a : b;
        }
        // bitonic sort of a bitonic sequence: stages d = 8,4,2,1
        #pragma unroll
        for (int d = 8; d >= 1; d >>= 1)
            #pragma unroll
            for (int j = 0; j < LISTN; ++j)
                if ((j & d) == 0) {
                    const unsigned x = c[j], y = c[j | d];
                    c[j] = x < y ? x : y;
                    c[j | d] = x < y ? y : x;
                }
        #pragma unroll
        for (int j = 0; j < LISTN; ++j) lk[j] = c[j];
    }

    // quad 0 lanes hold the final sorted top-16 for their row
    if (lane < 16) {
        unsigned* dst = cand + (size_t)myRow * (NCHUNK * LISTN) + chunk * LISTN;
        #pragma unroll
        for (int j = 0; j < LISTN; ++j) dst[j] = lk[j];
    }
}

// ---------------- Phase 3: prefilter 256->32 + parallel exact fp32 re-rank ----------------
// 8 rows/block, 32 lanes/row; width-32 shuffles.
__global__ __launch_bounds__(256) void knn_refine(
    const float* __restrict__ test, const float* __restrict__ train,
    const float* __restrict__ bsq, const unsigned* __restrict__ cand,
    int* __restrict__ out)
{
    __shared__ __align__(16) float sArow[RPB * K_DIM];   // 8 KB
    __shared__ int sSel[RPB * 32];                       // 1 KB

    const int tid = threadIdx.x;
    const int rowBase = blockIdx.x * RPB;
    const int r = tid >> 5;          // row 0..7
    const int sub = tid & 31;        // lane within row

    {
        const float4* src = (const float4*)(test + (size_t)rowBase * K_DIM);
        float4* dst = (float4*)sArow;
        dst[tid] = src[tid];
        dst[256 + tid] = src[256 + tid];
    }

    u64 ek[8];
    {
        const unsigned* cp = cand + (size_t)(rowBase + r) * 256 + sub * 8;
        #pragma unroll
        for (int j = 0; j < 8; ++j) {
            const unsigned k = cp[j];
            const int chunkId = (sub * 8 + j) >> 4;
            const unsigned gidx = (unsigned)(chunkId * CHUNK_N) + (k & 0xFFFu);
            ek[j] = ((u64)(k & 0xFFFFF000u) << 8) | gidx;
        }
    }
    __syncthreads();

    for (int sel = 0; sel < 32; ++sel) {
        u64 bk = ek[0];
        #pragma unroll
        for (int j = 1; j < 8; ++j) bk = (ek[j] < bk) ? ek[j] : bk;
        #pragma unroll
        for (int off = 16; off > 0; off >>= 1) {
            const u64 ok = __shfl_xor(bk, off, 32);
            bk = (ok < bk) ? ok : bk;
        }
        if (sub == 0) sSel[r * 32 + sel] = (int)(bk & 0xFFFFULL);
        #pragma unroll
        for (int j = 0; j < 8; ++j)
            if (ek[j] == bk) ek[j] = ~0ULL;
    }
    __syncthreads();

    const int gidx = sSel[r * 32 + sub];
    const float* arow = sArow + r * K_DIM;
    const float ta = np_pw_sq128(arow) + np_pw_sq128(arow + 128);
    const float tb = bsq[gidx];

    const float4* bp = (const float4*)(train + (size_t)gidx * K_DIM);
    const float4* ap = (const float4*)arow;
    float c = 0.0f;
    #pragma unroll 8
    for (int k = 0; k < K_DIM / 4; ++k) {
        const float4 a = ap[k];
        const float4 b = bp[k];
        c = fmaf(a.x, b.x, c); c = fmaf(a.y, b.y, c);
        c = fmaf(a.z, b.z, c); c = fmaf(a.w, b.w, c);
    }
    float d32;
    {
        #pragma clang fp contract(off)
        const float t = ta + tb;
        float s = t - 2.0f * c;
        s = fmaxf(s, 0.0f);
        d32 = sqrtf(s);
    }

    u64 fk = ((u64)__float_as_uint(d32) << 32) | (unsigned)gidx;
    for (int sel = 0; sel < 16; ++sel) {
        u64 bk = fk;
        #pragma unroll
        for (int off = 16; off > 0; off >>= 1) {
            const u64 ok = __shfl_xor(bk, off, 32);
            bk = (ok < bk) ? ok : bk;
        }
        if (sub == 0) out[(size_t)(rowBase + r) * 16 + sel] = (int)(bk & 0xFFFFFFFFULL);
        if (fk == bk) fk = ~0ULL;
    }
}

// ---------------- launch ----------------
extern "C" void kernel_launch(void* const* d_in, const int* in_sizes, int n_in,
                              void* d_out, int out_size, void* d_ws, size_t ws_size,
                              hipStream_t stream)
{
    const float* Xtrain = (const float*)d_in[0];   // [65536, 256]
    const float* Xtest  = (const float*)d_in[1];   // [4096, 256]
    int* out = (int*)d_out;                        // [4096, 16] int32

    const size_t OFF_TRAINBF = 0;                              // 33,554,432 B
    const size_t OFF_TESTBF  = 33554432;                       //  2,097,152 B
    const size_t OFF_BSQ     = 35651584;                       //    262,144 B
    const size_t OFF_CAND    = 35913728;                       //  4,194,304 B
    const size_t NEED        = 40108032;
    if (ws_size < NEED) return;

    char* ws = (char*)d_ws;
    ushort_t* trainBf = (ushort_t*)(ws + OFF_TRAINBF);
    ushort_t* testBf  = (ushort_t*)(ws + OFF_TESTBF);
    float*    bsq     = (float*)(ws + OFF_BSQ);
    unsigned* cand    = (unsigned*)(ws + OFF_CAND);

    convert_bf16<<<dim3(N_TRAIN / 4), dim3(256), 0, stream>>>(Xtrain, trainBf, N_TRAIN);
    convert_bf16<<<dim3(N_TEST / 4), dim3(256), 0, stream>>>(Xtest, testBf, N_TEST);
    train_sq_np<<<dim3(N_TRAIN / 256), dim3(256), 0, stream>>>(Xtrain, bsq);
    knn_approx<<<dim3((N_TEST / TM) * NCHUNK), dim3(512), 0, stream>>>(testBf, trainBf, bsq, cand);
    knn_refine<<<dim3(N_TEST / RPB), dim3(256), 0, stream>>>(Xtest, Xtrain, bsq, cand, out);
}

// Round 15
// 591.335 us; speedup vs baseline: 1.3854x; 1.3854x over previous
//
#include <hip/hip_runtime.h>
#include <hip/hip_bf16.h>

// KNN top-16: X_test[4096,256] vs X_train[65536,256], fp32 in, int32 idx out.
// Phase 1: fp32->bf16 convert; fp32 train row sq-norms (numpy-pairwise emulation).
// Phase 2: approx score GEMM (v = ||b||^2 - 2 a.b) on 32x32x16 MFMA, swapped
//          operands: mfma(train_A, test_B, acc) -> D[train_col][test_row].
//          R11 residual wall = LDS pipe (512 b128-insts/block-iter ~ saturated).
//          R13: TM=64, 8 waves = 2 rowgrp x 4 colgrp, wave = 32 rows x 32 cols.
//          32x32x16 gives 16K MACs per b128 A-read (2x 16x16x32) and colgrp
//          split cuts col redundancy 8x->2x: LDS reads/iter/lane 64 -> 16.
//          sB staged [kgroup][col] (lane-contiguous b128 reads); staging source
//          address absorbs the transpose (dest linear per gld_lds constraint).
//          Per-thread: one test row (lane&31), 16 cols/iter in regs; R11 FIFO
//          selection (flush every 2 iters); chunk-end: shfl_xor(32) bitonic +
//          4-way LDS merge across colgrp waves. Regs ~115 <= 128 (R12 spilled
//          at ~145 -> reverted). D-layout col=l&31,row=(reg&3)+8(reg>>2)+4(l>>5)
//          per guide-verified m74/m101.
// Phase 3: 8 rows/block: approx-top-32 prefilter of 256 candidates (width-32
//          shuffles), then 256 parallel exact fp32-reference-emulating chains,
//          lex (d32, gidx) top-16 (fp32 snap-ties resolve by index like top_k).

typedef short bf16x8 __attribute__((ext_vector_type(8)));
typedef float f32x16 __attribute__((ext_vector_type(16)));
typedef unsigned short ushort_t;
typedef unsigned long long u64;

#define K_DIM     256
#define N_TRAIN   65536
#define N_TEST    4096
#define TM        64
#define TN        128
#define NCHUNK    16
#define CHUNK_N   (N_TRAIN / NCHUNK)      // 4096
#define ITERS     (CHUNK_N / TN)          // 32
#define LISTN     16
#define RPB       8                        // refine rows per block
#define SENT      0xFFFFFFFFu

// ---------------- numpy pairwise sum emulation (fp32, contract OFF) ----------------
static __device__ __forceinline__ float np_pw_sq128(const float* __restrict__ x) {
    #pragma clang fp contract(off)
    float r0, r1, r2, r3, r4, r5, r6, r7;
    {
        const float4 a = *(const float4*)(x + 0);
        const float4 b = *(const float4*)(x + 4);
        r0 = a.x * a.x; r1 = a.y * a.y; r2 = a.z * a.z; r3 = a.w * a.w;
        r4 = b.x * b.x; r5 = b.y * b.y; r6 = b.z * b.z; r7 = b.w * b.w;
    }
    for (int i = 8; i < 128; i += 8) {
        const float4 a = *(const float4*)(x + i);
        const float4 b = *(const float4*)(x + i + 4);
        r0 = r0 + a.x * a.x; r1 = r1 + a.y * a.y;
        r2 = r2 + a.z * a.z; r3 = r3 + a.w * a.w;
        r4 = r4 + b.x * b.x; r5 = r5 + b.y * b.y;
        r6 = r6 + b.z * b.z; r7 = r7 + b.w * b.w;
    }
    return ((r0 + r1) + (r2 + r3)) + ((r4 + r5) + (r6 + r7));
}

// ---------------- async global->LDS, 16B per lane ----------------
static __device__ __forceinline__ void gld_lds16(const ushort_t* g, ushort_t* l) {
    __builtin_amdgcn_global_load_lds(
        (const __attribute__((address_space(1))) unsigned int*)g,
        (__attribute__((address_space(3))) unsigned int*)l,
        16, 0, 0);
}

// ---------------- Phase 1a: convert ----------------
static __device__ __forceinline__ ushort_t f2bf(float x) {
    unsigned u = __float_as_uint(x);
    return (ushort_t)((u + 0x7FFFu + ((u >> 16) & 1u)) >> 16);  // RNE
}

__global__ __launch_bounds__(256) void convert_bf16(
    const float* __restrict__ src, ushort_t* __restrict__ dst, int nrows)
{
    const int wid = threadIdx.x >> 6, lane = threadIdx.x & 63;
    const int row = blockIdx.x * 4 + wid;
    if (row >= nrows) return;
    const float4 f = *(const float4*)(src + (size_t)row * K_DIM + lane * 4);
    ushort4 h;
    h.x = f2bf(f.x); h.y = f2bf(f.y); h.z = f2bf(f.z); h.w = f2bf(f.w);
    *(ushort4*)(dst + (size_t)row * K_DIM + lane * 4) = h;
}

// ---------------- Phase 1b: train row norms, numpy-pairwise fp32 ----------------
__global__ __launch_bounds__(256) void train_sq_np(
    const float* __restrict__ train, float* __restrict__ bsq)
{
    const int r = blockIdx.x * 256 + threadIdx.x;
    const float* x = train + (size_t)r * K_DIM;
    bsq[r] = np_pw_sq128(x) + np_pw_sq128(x + 128);
}

// ---------------- Phase 2: 32x32 swapped GEMM + FIFO register top-16 ----------------
// 512 thr, 8 waves = 2 rowgrp x 4 colgrp; wave = 32 test rows x 32 train cols.
// sB [16 kgroups][128 cols] x 8 bf16; A(train) from sB, B(test) resident regs.
__global__ __launch_bounds__(512, 4) void knn_approx(
    const ushort_t* __restrict__ testBf, const ushort_t* __restrict__ trainBf,
    const float* __restrict__ bsq, unsigned* __restrict__ cand)
{
    __shared__ __align__(16) ushort_t sB[16 * TN * 8];  // 32 KB: [kgrp][col][8]
    __shared__ __align__(16) float    sBsq[TN];         // 512 B (bsq + 1024)

    const int tid = threadIdx.x;
    const int bx = blockIdx.x;
    const int chunk = bx & (NCHUNK - 1);               // bx%8 = chunk%8 -> chunk-per-XCD
    const int rowTile = bx >> 4;                       // 0..63
    const int rowBase = rowTile * TM;
    const int chunkBase = chunk * CHUNK_N;
    const int lane = tid & 63;
    const int wid = tid >> 6;                          // 0..7
    const int rg = wid >> 2;                           // 0..1 row-group (32 rows)
    const int cg = wid & 3;                            // 0..3 col-group (32 cols)
    const int l31 = lane & 31;
    const int hi = lane >> 5;                          // k-half within frag

    // my test row (one per thread; lanes l and l+32 share a row, disjoint cols)
    const int myRow = rowBase + rg * 32 + l31;

    // register-resident top-16 (packed keys), ascending; sentinel+0x1000 = +inf
    unsigned lk[LISTN];
    #pragma unroll
    for (int j = 0; j < LISTN; ++j) lk[j] = 0x7F7FF000u | (unsigned)j;

    auto cins = [&](unsigned k) {
        if (k < lk[LISTN - 1]) {
            lk[LISTN - 1] = k;
            #pragma unroll
            for (int j = LISTN - 1; j > 0; --j)
                if (lk[j] < lk[j - 1]) {
                    const unsigned t = lk[j]; lk[j] = lk[j - 1]; lk[j - 1] = t;
                }
        }
    };

    unsigned q0 = SENT, q1 = SENT, q2 = SENT, q3 = SENT;
    float cutFp = __uint_as_float((lk[LISTN - 1] & 0xFFFFF000u) + 0x1000u);  // +inf

    // ---- preload B-operand (test row myRow, all K=256; 16 frags = 64 VGPR) ----
    // B[k][col]: lane holds col (l&31) = myRow, k = s*16 + hi*8 + j
    bf16x8 af[16];
    {
        const ushort_t* a0 = testBf + (size_t)myRow * K_DIM + hi * 8;
        #pragma unroll
        for (int s = 0; s < 16; ++s)
            af[s] = *(const bf16x8*)(a0 + s * 16);
    }

    // staging map: col = tid&127 (const), kgrp = c*4 + (tid>>7)
    const int scol = tid & 127;
    const int sgb  = tid >> 7;                         // 0..3

    for (int it = 0; it < ITERS; ++it) {
        const int colBase = chunkBase + it * TN;
        f32x16 acc = {};                               // 16 cols of my row

        #pragma unroll
        for (int p = 0; p < 2; ++p) {
            __syncthreads();           // protect sB against prior panel's reads
            {
                const ushort_t* gb = trainBf + (size_t)(colBase + scol) * K_DIM + p * 128 + sgb * 8;
                ushort_t* lb = sB + (size_t)tid * 8;   // slot c*512+tid, linear per c
                #pragma unroll
                for (int c = 0; c < 4; ++c)
                    gld_lds16(gb + (size_t)c * 32, lb + (size_t)c * 4096);
            }
            if (p == 0 && tid < TN) sBsq[tid] = bsq[colBase + tid] + 1024.0f;
            __syncthreads();           // drains vmcnt -> LDS valid

            #pragma unroll
            for (int sp = 0; sp < 8; ++sp) {
                // A(train): lane holds row (train col) cg*32+l31, k = sp*16+hi*8+j
                const int g = sp * 2 + hi;             // kgroup within panel
                const bf16x8 ta = *(const bf16x8*)(sB + ((size_t)g * TN + cg * 32 + l31) * 8);
                acc = __builtin_amdgcn_mfma_f32_32x32x16_bf16(ta, af[p * 8 + sp], acc, 0, 0, 0);
            }
        }

        // epilogue: D row r -> train col cg*32 + (r&3) + 8*(r>>2) + 4*hi
        const float* bqb = sBsq + cg * 32 + hi * 4;
        const float4 bq0 = *(const float4*)(bqb + 0);
        const float4 bq1 = *(const float4*)(bqb + 8);
        const float4 bq2 = *(const float4*)(bqb + 16);
        const float4 bq3 = *(const float4*)(bqb + 24);
        const unsigned colb = (unsigned)(it * TN + cg * 32 + hi * 4);
        #pragma unroll
        for (int r = 0; r < 16; ++r) {
            const float4 bq4 = (r < 4) ? bq0 : (r < 8) ? bq1 : (r < 12) ? bq2 : bq3;
            const int rr = r & 3;
            const float bq = (rr == 0) ? bq4.x : (rr == 1) ? bq4.y : (rr == 2) ? bq4.z : bq4.w;
            const float v = fmaf(-2.0f, acc[r], bq);
            if (v < cutFp) {                           // 1-op pretest (superset)
                cins(q3);                              // overflow-preserve (SENT fails)
                q3 = q2; q2 = q1; q1 = q0;
                q0 = (__float_as_uint(v) & 0xFFFFF000u) | (colb + (unsigned)(r & 3) + 8u * (unsigned)(r >> 2));
            }
        }

        if (it & 1) {                                  // flush every 2 iters (32 slots)
            cins(q3); cins(q2); cins(q1); cins(q0);
            q0 = SENT; q1 = SENT; q2 = SENT; q3 = SENT;
            cutFp = __uint_as_float((lk[LISTN - 1] & 0xFFFFF000u) + 0x1000u);
        }
    }

    // ---- merge lane l <-> l+32 (same row, disjoint cols): one bitonic step ----
    {
        unsigned other[LISTN];
        #pragma unroll
        for (int j = 0; j < LISTN; ++j)
            other[j] = (unsigned)__shfl_xor((int)lk[j], 32, 64);
        unsigned c[LISTN];
        #pragma unroll
        for (int j = 0; j < LISTN; ++j) {
            const unsigned a = lk[j], b = other[LISTN - 1 - j];
            c[j] = a < b ? a : b;
        }
        #pragma unroll
        for (int d = 8; d >= 1; d >>= 1)
            #pragma unroll
            for (int j = 0; j < LISTN; ++j)
                if ((j & d) == 0) {
                    const unsigned x = c[j], y = c[j | d];
                    c[j] = x < y ? x : y;
                    c[j | d] = x < y ? y : x;
                }
        #pragma unroll
        for (int j = 0; j < LISTN; ++j) lk[j] = c[j];
    }

    // ---- cross-colgrp merge via LDS scratch (reuse sB), once per kernel ----
    __syncthreads();                                   // all waves done reading sB
    unsigned* scr = (unsigned*)sB;                     // [8 wid][32 rows][16]
    if (lane < 32) {
        unsigned* dst = scr + ((size_t)wid * 32 + l31) * LISTN;
        #pragma unroll
        for (int j = 0; j < LISTN; ++j) dst[j] = lk[j];
    }
    __syncthreads();
    if (tid < TM) {                                    // one thread per row
        const int rgo = tid >> 5;                      // row-group
        const int r32 = tid & 31;
        const unsigned* L0 = scr + ((size_t)(rgo * 4 + 0) * 32 + r32) * LISTN;
        const unsigned* L1 = scr + ((size_t)(rgo * 4 + 1) * 32 + r32) * LISTN;
        const unsigned* L2 = scr + ((size_t)(rgo * 4 + 2) * 32 + r32) * LISTN;
        const unsigned* L3 = scr + ((size_t)(rgo * 4 + 3) * 32 + r32) * LISTN;
        unsigned* dst = cand + (size_t)(rowBase + tid) * (NCHUNK * LISTN) + chunk * LISTN;
        int i0 = 0, i1 = 0, i2 = 0, i3 = 0;
        #pragma unroll
        for (int j = 0; j < LISTN; ++j) {              // 4-way merge (keys unique)
            const unsigned v0 = L0[i0], v1 = L1[i1], v2 = L2[i2], v3 = L3[i3];
            const unsigned m01 = v0 < v1 ? v0 : v1;
            const unsigned m23 = v2 < v3 ? v2 : v3;
            const unsigned m = m01 < m23 ? m01 : m23;
            dst[j] = m;
            if (v0 == m)      ++i0;
            else if (v1 == m) ++i1;
            else if (v2 == m) ++i2;
            else              ++i3;
        }
    }
}

// ---------------- Phase 3: prefilter 256->32 + parallel exact fp32 re-rank ----------------
// 8 rows/block, 32 lanes/row; width-32 shuffles.
__global__ __launch_bounds__(256) void knn_refine(
    const float* __restrict__ test, const float* __restrict__ train,
    const float* __restrict__ bsq, const unsigned* __restrict__ cand,
    int* __restrict__ out)
{
    __shared__ __align__(16) float sArow[RPB * K_DIM];   // 8 KB
    __shared__ int sSel[RPB * 32];                       // 1 KB

    const int tid = threadIdx.x;
    const int rowBase = blockIdx.x * RPB;
    const int r = tid >> 5;          // row 0..7
    const int sub = tid & 31;        // lane within row

    {
        const float4* src = (const float4*)(test + (size_t)rowBase * K_DIM);
        float4* dst = (float4*)sArow;
        dst[tid] = src[tid];
        dst[256 + tid] = src[256 + tid];
    }

    u64 ek[8];
    {
        const unsigned* cp = cand + (size_t)(rowBase + r) * 256 + sub * 8;
        #pragma unroll
        for (int j = 0; j < 8; ++j) {
            const unsigned k = cp[j];
            const int chunkId = (sub * 8 + j) >> 4;
            const unsigned gidx = (unsigned)(chunkId * CHUNK_N) + (k & 0xFFFu);
            ek[j] = ((u64)(k & 0xFFFFF000u) << 8) | gidx;
        }
    }
    __syncthreads();

    for (int sel = 0; sel < 32; ++sel) {
        u64 bk = ek[0];
        #pragma unroll
        for (int j = 1; j < 8; ++j) bk = (ek[j] < bk) ? ek[j] : bk;
        #pragma unroll
        for (int off = 16; off > 0; off >>= 1) {
            const u64 ok = __shfl_xor(bk, off, 32);
            bk = (ok < bk) ? ok : bk;
        }
        if (sub == 0) sSel[r * 32 + sel] = (int)(bk & 0xFFFFULL);
        #pragma unroll
        for (int j = 0; j < 8; ++j)
            if (ek[j] == bk) ek[j] = ~0ULL;
    }
    __syncthreads();

    const int gidx = sSel[r * 32 + sub];
    const float* arow = sArow + r * K_DIM;
    const float ta = np_pw_sq128(arow) + np_pw_sq128(arow + 128);
    const float tb = bsq[gidx];

    const float4* bp = (const float4*)(train + (size_t)gidx * K_DIM);
    const float4* ap = (const float4*)arow;
    float c = 0.0f;
    #pragma unroll 8
    for (int k = 0; k < K_DIM / 4; ++k) {
        const float4 a = ap[k];
        const float4 b = bp[k];
        c = fmaf(a.x, b.x, c); c = fmaf(a.y, b.y, c);
        c = fmaf(a.z, b.z, c); c = fmaf(a.w, b.w, c);
    }
    float d32;
    {
        #pragma clang fp contract(off)
        const float t = ta + tb;
        float s = t - 2.0f * c;
        s = fmaxf(s, 0.0f);
        d32 = sqrtf(s);
    }

    u64 fk = ((u64)__float_as_uint(d32) << 32) | (unsigned)gidx;
    for (int sel = 0; sel < 16; ++sel) {
        u64 bk = fk;
        #pragma unroll
        for (int off = 16; off > 0; off >>= 1) {
            const u64 ok = __shfl_xor(bk, off, 32);
            bk = (ok < bk) ? ok : bk;
        }
        if (sub == 0) out[(size_t)(rowBase + r) * 16 + sel] = (int)(bk & 0xFFFFFFFFULL);
        if (fk == bk) fk = ~0ULL;
    }
}

// ---------------- launch ----------------
extern "C" void kernel_launch(void* const* d_in, const int* in_sizes, int n_in,
                              void* d_out, int out_size, void* d_ws, size_t ws_size,
                              hipStream_t stream)
{
    const float* Xtrain = (const float*)d_in[0];   // [65536, 256]
    const float* Xtest  = (const float*)d_in[1];   // [4096, 256]
    int* out = (int*)d_out;                        // [4096, 16] int32

    const size_t OFF_TRAINBF = 0;                              // 33,554,432 B
    const size_t OFF_TESTBF  = 33554432;                       //  2,097,152 B
    const size_t OFF_BSQ     = 35651584;                       //    262,144 B
    const size_t OFF_CAND    = 35913728;                       //  4,194,304 B
    const size_t NEED        = 40108032;
    if (ws_size < NEED) return;

    char* ws = (char*)d_ws;
    ushort_t* trainBf = (ushort_t*)(ws + OFF_TRAINBF);
    ushort_t* testBf  = (ushort_t*)(ws + OFF_TESTBF);
    float*    bsq     = (float*)(ws + OFF_BSQ);
    unsigned* cand    = (unsigned*)(ws + OFF_CAND);

    convert_bf16<<<dim3(N_TRAIN / 4), dim3(256), 0, stream>>>(Xtrain, trainBf, N_TRAIN);
    convert_bf16<<<dim3(N_TEST / 4), dim3(256), 0, stream>>>(Xtest, testBf, N_TEST);
    train_sq_np<<<dim3(N_TRAIN / 256), dim3(256), 0, stream>>>(Xtrain, bsq);
    knn_approx<<<dim3((N_TEST / TM) * NCHUNK), dim3(512), 0, stream>>>(testBf, trainBf, bsq, cand);
    knn_refine<<<dim3(N_TEST / RPB), dim3(256), 0, stream>>>(Xtest, Xtrain, bsq, cand, out);
}